// Round 2
// baseline (117.073 us; speedup 1.0000x reference)
//
#include <hip/hip_runtime.h>

#define NTHREADS 256
#define MAXBLOCKS 2048

__global__ __launch_bounds__(NTHREADS) void pareto_fused(
    const float* __restrict__ y,
    const float* __restrict__ alpha,
    const int* __restrict__ xm_p,
    float* __restrict__ partials,
    unsigned int* __restrict__ counter,
    float* __restrict__ out,
    int n)
{
    const float xm = (float)xm_p[0];
    const int n4 = n >> 2;
    const float4* __restrict__ y4 = (const float4*)y;
    const float4* __restrict__ a4 = (const float4*)alpha;

    float acc = 0.0f;
    const int stride = gridDim.x * blockDim.x;
    int i = blockIdx.x * blockDim.x + threadIdx.x;

    // unroll x2: 4 independent 16B loads in flight per iteration
    for (; i + stride < n4; i += 2 * stride) {
        float4 ya = y4[i];
        float4 aa = a4[i];
        float4 yb = y4[i + stride];
        float4 ab = a4[i + stride];

        float t0 = __logf(aa.x) * xm - (aa.x + 1.0f) * __logf(ya.x);
        float t1 = __logf(aa.y) * xm - (aa.y + 1.0f) * __logf(ya.y);
        float t2 = __logf(aa.z) * xm - (aa.z + 1.0f) * __logf(ya.z);
        float t3 = __logf(aa.w) * xm - (aa.w + 1.0f) * __logf(ya.w);
        acc += (ya.x > 0.0f) ? t0 : 0.0f;
        acc += (ya.y > 0.0f) ? t1 : 0.0f;
        acc += (ya.z > 0.0f) ? t2 : 0.0f;
        acc += (ya.w > 0.0f) ? t3 : 0.0f;

        float u0 = __logf(ab.x) * xm - (ab.x + 1.0f) * __logf(yb.x);
        float u1 = __logf(ab.y) * xm - (ab.y + 1.0f) * __logf(yb.y);
        float u2 = __logf(ab.z) * xm - (ab.z + 1.0f) * __logf(yb.z);
        float u3 = __logf(ab.w) * xm - (ab.w + 1.0f) * __logf(yb.w);
        acc += (yb.x > 0.0f) ? u0 : 0.0f;
        acc += (yb.y > 0.0f) ? u1 : 0.0f;
        acc += (yb.z > 0.0f) ? u2 : 0.0f;
        acc += (yb.w > 0.0f) ? u3 : 0.0f;
    }
    for (; i < n4; i += stride) {
        float4 ya = y4[i];
        float4 aa = a4[i];
        float t0 = __logf(aa.x) * xm - (aa.x + 1.0f) * __logf(ya.x);
        float t1 = __logf(aa.y) * xm - (aa.y + 1.0f) * __logf(ya.y);
        float t2 = __logf(aa.z) * xm - (aa.z + 1.0f) * __logf(ya.z);
        float t3 = __logf(aa.w) * xm - (aa.w + 1.0f) * __logf(ya.w);
        acc += (ya.x > 0.0f) ? t0 : 0.0f;
        acc += (ya.y > 0.0f) ? t1 : 0.0f;
        acc += (ya.z > 0.0f) ? t2 : 0.0f;
        acc += (ya.w > 0.0f) ? t3 : 0.0f;
    }

    // tail (n not multiple of 4) — one thread, precise logf is fine here
    if (blockIdx.x == 0 && threadIdx.x == 0) {
        for (int j = n4 << 2; j < n; ++j) {
            float yv = y[j];
            if (yv > 0.0f) {
                float av = alpha[j];
                acc += __logf(av) * xm - (av + 1.0f) * __logf(yv);
            }
        }
    }

    // wave-64 reduction
    #pragma unroll
    for (int off = 32; off > 0; off >>= 1)
        acc += __shfl_down(acc, off, 64);

    __shared__ float wsum[NTHREADS / 64];
    __shared__ int isLast;
    const int lane = threadIdx.x & 63;
    const int wid  = threadIdx.x >> 6;
    if (lane == 0) wsum[wid] = acc;
    __syncthreads();

    if (threadIdx.x == 0) {
        float s = 0.0f;
        #pragma unroll
        for (int w = 0; w < NTHREADS / 64; ++w) s += wsum[w];
        partials[blockIdx.x] = s;
        __threadfence();  // release: partial visible device-wide before ticket
        unsigned int t = atomicAdd(counter, 1u);
        isLast = (t == gridDim.x - 1) ? 1 : 0;
    }
    __syncthreads();

    if (isLast) {
        __threadfence();  // acquire: see all blocks' partials
        double d = 0.0;
        for (int j = threadIdx.x; j < (int)gridDim.x; j += NTHREADS)
            d += (double)partials[j];
        __shared__ double ds[NTHREADS];
        ds[threadIdx.x] = d;
        __syncthreads();
        #pragma unroll
        for (int off = NTHREADS / 2; off > 0; off >>= 1) {
            if (threadIdx.x < off) ds[threadIdx.x] += ds[threadIdx.x + off];
            __syncthreads();
        }
        if (threadIdx.x == 0) out[0] = (float)(-ds[0]);
    }
}

extern "C" void kernel_launch(void* const* d_in, const int* in_sizes, int n_in,
                              void* d_out, int out_size, void* d_ws, size_t ws_size,
                              hipStream_t stream)
{
    const float* y     = (const float*)d_in[0];
    const float* alpha = (const float*)d_in[1];
    const int*   xm    = (const int*)d_in[2];
    float* out = (float*)d_out;

    float* partials = (float*)d_ws;                            // MAXBLOCKS floats
    unsigned int* counter = (unsigned int*)((char*)d_ws + MAXBLOCKS * sizeof(float));

    const int n = in_sizes[0];
    int n4 = n >> 2;
    int grid = (n4 + NTHREADS - 1) / NTHREADS;
    if (grid > MAXBLOCKS) grid = MAXBLOCKS;
    if (grid < 1) grid = 1;

    hipMemsetAsync(counter, 0, sizeof(unsigned int), stream);
    pareto_fused<<<grid, NTHREADS, 0, stream>>>(y, alpha, xm, partials, counter, out, n);
}

// Round 3
// 51.894 us; speedup vs baseline: 2.2560x; 2.2560x over previous
//
#include <hip/hip_runtime.h>

#define NBLOCKS 2048
#define NTHREADS 256

__global__ __launch_bounds__(NTHREADS) void pareto_partial(
    const float* __restrict__ y,
    const float* __restrict__ alpha,
    const int* __restrict__ xm_p,
    float* __restrict__ partials,
    int n)
{
    const float xm = (float)xm_p[0];
    const int n4 = n >> 2;
    const float4* __restrict__ y4 = (const float4*)y;
    const float4* __restrict__ a4 = (const float4*)alpha;

    float acc0 = 0.0f, acc1 = 0.0f;
    const int stride = gridDim.x * blockDim.x;
    int i = blockIdx.x * blockDim.x + threadIdx.x;

    // unroll x2, two independent accumulators; branch-guarded as in R1.
    for (; i + stride < n4; i += 2 * stride) {
        float4 ya = y4[i];
        float4 aa = a4[i];
        float4 yb = y4[i + stride];
        float4 ab = a4[i + stride];

        if (ya.x > 0.0f) acc0 += logf(aa.x) * xm - (aa.x + 1.0f) * logf(ya.x);
        if (ya.y > 0.0f) acc0 += logf(aa.y) * xm - (aa.y + 1.0f) * logf(ya.y);
        if (ya.z > 0.0f) acc0 += logf(aa.z) * xm - (aa.z + 1.0f) * logf(ya.z);
        if (ya.w > 0.0f) acc0 += logf(aa.w) * xm - (aa.w + 1.0f) * logf(ya.w);

        if (yb.x > 0.0f) acc1 += logf(ab.x) * xm - (ab.x + 1.0f) * logf(yb.x);
        if (yb.y > 0.0f) acc1 += logf(ab.y) * xm - (ab.y + 1.0f) * logf(yb.y);
        if (yb.z > 0.0f) acc1 += logf(ab.z) * xm - (ab.z + 1.0f) * logf(yb.z);
        if (yb.w > 0.0f) acc1 += logf(ab.w) * xm - (ab.w + 1.0f) * logf(yb.w);
    }
    for (; i < n4; i += stride) {
        float4 ya = y4[i];
        float4 aa = a4[i];
        if (ya.x > 0.0f) acc0 += logf(aa.x) * xm - (aa.x + 1.0f) * logf(ya.x);
        if (ya.y > 0.0f) acc0 += logf(aa.y) * xm - (aa.y + 1.0f) * logf(ya.y);
        if (ya.z > 0.0f) acc0 += logf(aa.z) * xm - (aa.z + 1.0f) * logf(ya.z);
        if (ya.w > 0.0f) acc0 += logf(aa.w) * xm - (aa.w + 1.0f) * logf(ya.w);
    }
    float acc = acc0 + acc1;

    // tail (n not multiple of 4) — one thread
    if (blockIdx.x == 0 && threadIdx.x == 0) {
        for (int j = n4 << 2; j < n; ++j) {
            float yv = y[j];
            if (yv > 0.0f) {
                float av = alpha[j];
                acc += logf(av) * xm - (av + 1.0f) * logf(yv);
            }
        }
    }

    // wave-64 reduction
    #pragma unroll
    for (int off = 32; off > 0; off >>= 1)
        acc += __shfl_down(acc, off, 64);

    __shared__ float wsum[NTHREADS / 64];
    const int lane = threadIdx.x & 63;
    const int wid  = threadIdx.x >> 6;
    if (lane == 0) wsum[wid] = acc;
    __syncthreads();
    if (threadIdx.x == 0) {
        float s = 0.0f;
        #pragma unroll
        for (int w = 0; w < NTHREADS / 64; ++w) s += wsum[w];
        partials[blockIdx.x] = s;
    }
}

__global__ __launch_bounds__(256) void pareto_final(
    const float* __restrict__ partials,
    float* __restrict__ out,
    int nb)
{
    // deterministic fixed-order double accumulation
    double acc = 0.0;
    for (int i = threadIdx.x; i < nb; i += 256)
        acc += (double)partials[i];

    __shared__ double s[256];
    s[threadIdx.x] = acc;
    __syncthreads();
    #pragma unroll
    for (int off = 128; off > 0; off >>= 1) {
        if (threadIdx.x < off) s[threadIdx.x] += s[threadIdx.x + off];
        __syncthreads();
    }
    if (threadIdx.x == 0) out[0] = (float)(-s[0]);
}

extern "C" void kernel_launch(void* const* d_in, const int* in_sizes, int n_in,
                              void* d_out, int out_size, void* d_ws, size_t ws_size,
                              hipStream_t stream)
{
    const float* y     = (const float*)d_in[0];
    const float* alpha = (const float*)d_in[1];
    const int*   xm    = (const int*)d_in[2];
    float* out = (float*)d_out;
    float* partials = (float*)d_ws;   // NBLOCKS floats = 8 KB scratch

    const int n = in_sizes[0];
    int n4 = n >> 2;
    int grid = (n4 + NTHREADS - 1) / NTHREADS;
    if (grid > NBLOCKS) grid = NBLOCKS;
    if (grid < 1) grid = 1;

    pareto_partial<<<grid, NTHREADS, 0, stream>>>(y, alpha, xm, partials, n);
    pareto_final<<<1, 256, 0, stream>>>(partials, out, grid);
}

// Round 4
// 50.616 us; speedup vs baseline: 2.3130x; 1.0253x over previous
//
#include <hip/hip_runtime.h>

#define NBLOCKS 2048
#define NTHREADS 256

__global__ __launch_bounds__(NTHREADS) void pareto_partial(
    const float* __restrict__ y,
    const float* __restrict__ alpha,
    const int* __restrict__ xm_p,
    float* __restrict__ partials,
    int n)
{
    const float xm = (float)xm_p[0];
    const int n4 = n >> 2;
    const float4* __restrict__ y4 = (const float4*)y;
    const float4* __restrict__ a4 = (const float4*)alpha;

    float acc = 0.0f;
    const int stride = gridDim.x * blockDim.x;
    // R1 structure (simple grid-stride, low VGPR, high occupancy);
    // only change: __logf (hw v_log_f32) instead of precise logf.
    for (int i = blockIdx.x * blockDim.x + threadIdx.x; i < n4; i += stride) {
        float4 yv = y4[i];
        float4 av = a4[i];
        if (yv.x > 0.0f) acc += __logf(av.x) * xm - (av.x + 1.0f) * __logf(yv.x);
        if (yv.y > 0.0f) acc += __logf(av.y) * xm - (av.y + 1.0f) * __logf(yv.y);
        if (yv.z > 0.0f) acc += __logf(av.z) * xm - (av.z + 1.0f) * __logf(yv.z);
        if (yv.w > 0.0f) acc += __logf(av.w) * xm - (av.w + 1.0f) * __logf(yv.w);
    }

    // tail (n not multiple of 4) — one thread
    if (blockIdx.x == 0 && threadIdx.x == 0) {
        for (int i = n4 << 2; i < n; ++i) {
            float yv = y[i];
            if (yv > 0.0f) {
                float av = alpha[i];
                acc += __logf(av) * xm - (av + 1.0f) * __logf(yv);
            }
        }
    }

    // wave-64 reduction
    #pragma unroll
    for (int off = 32; off > 0; off >>= 1)
        acc += __shfl_down(acc, off, 64);

    __shared__ float wsum[NTHREADS / 64];
    const int lane = threadIdx.x & 63;
    const int wid  = threadIdx.x >> 6;
    if (lane == 0) wsum[wid] = acc;
    __syncthreads();
    if (threadIdx.x == 0) {
        float s = 0.0f;
        #pragma unroll
        for (int w = 0; w < NTHREADS / 64; ++w) s += wsum[w];
        partials[blockIdx.x] = s;
    }
}

// single-wave final reduction: no LDS, no barriers, fixed-order double sum
__global__ __launch_bounds__(64) void pareto_final(
    const float* __restrict__ partials,
    float* __restrict__ out,
    int nb)
{
    const int lane = threadIdx.x;
    double acc = 0.0;
    for (int i = lane; i < nb; i += 64)
        acc += (double)partials[i];

    #pragma unroll
    for (int off = 32; off > 0; off >>= 1)
        acc += __shfl_down(acc, off, 64);

    if (lane == 0) out[0] = (float)(-acc);
}

extern "C" void kernel_launch(void* const* d_in, const int* in_sizes, int n_in,
                              void* d_out, int out_size, void* d_ws, size_t ws_size,
                              hipStream_t stream)
{
    const float* y     = (const float*)d_in[0];
    const float* alpha = (const float*)d_in[1];
    const int*   xm    = (const int*)d_in[2];
    float* out = (float*)d_out;
    float* partials = (float*)d_ws;   // NBLOCKS floats = 8 KB scratch

    const int n = in_sizes[0];
    int n4 = n >> 2;
    int grid = (n4 + NTHREADS - 1) / NTHREADS;
    if (grid > NBLOCKS) grid = NBLOCKS;
    if (grid < 1) grid = 1;

    pareto_partial<<<grid, NTHREADS, 0, stream>>>(y, alpha, xm, partials, n);
    pareto_final<<<1, 64, 0, stream>>>(partials, out, grid);
}